// Round 4
// baseline (301.741 us; speedup 1.0000x reference)
//
#include <hip/hip_runtime.h>
#include <hip/hip_bf16.h>
#include <math.h>

typedef unsigned short ushort_t;
typedef unsigned char uchar_t;
typedef unsigned int uint_t;
typedef __attribute__((ext_vector_type(8))) short bf16x8;   // 8 bf16 = 4 VGPRs
typedef __attribute__((ext_vector_type(4))) float f32x4;

#define AS1 __attribute__((address_space(1)))
#define AS3 __attribute__((address_space(3)))

__device__ __forceinline__ void gld_lds16(const void* g, void* l) {
  // async global->LDS, 16B per lane; LDS dest = wave-uniform base + lane*16
  __builtin_amdgcn_global_load_lds((const AS1 void*)g, (AS3 void*)l, 16, 0, 0);
}

__device__ __forceinline__ ushort_t f32_to_bf16_bits(float v) {
  __hip_bfloat16 b = __float2bfloat16(v);
  return *(ushort_t*)&b;
}

// ---------------- single prep kernel ----------------
// blocks [0, normBlocks): wave-per-row L2-normalize of h then prototypes,
//   output fp8 e4m3 at scale x4 (elements ~N(0,1/sqrt768); x4 escapes denormals,
//   dot comes out x16, undone in GEMM1 epilogue).
// blocks [normBlocks, ...): 32x32 transpose of prototype_class [P,C] f32 ->
//   pcT [CP,P] bf16, zero-padding cols >= C.
__global__ __launch_bounds__(256) void prep(const float4* __restrict__ h,
                                            uint_t* __restrict__ h8, int rowsH,
                                            const float4* __restrict__ p,
                                            uint_t* __restrict__ p8, int rowsP,
                                            const float* __restrict__ pc,
                                            ushort_t* __restrict__ pcT,
                                            int P, int C, int normBlocks) {
  __shared__ float tile[32][33];
  if ((int)blockIdx.x < normBlocks) {
    int gwave = (blockIdx.x * 256 + threadIdx.x) >> 6;
    const int lane = threadIdx.x & 63;
    const float4* xr;
    uint_t* orow;
    if (gwave < rowsH) {
      xr = h + (size_t)gwave * 192;          // 768 floats = 192 float4
      orow = h8 + (size_t)gwave * 192;       // 768 fp8 = 192 uint
    } else {
      gwave -= rowsH;
      if (gwave >= rowsP) return;
      xr = p + (size_t)gwave * 192;
      orow = p8 + (size_t)gwave * 192;
    }
    float4 v0 = xr[lane];
    float4 v1 = xr[lane + 64];
    float4 v2 = xr[lane + 128];
    float ss = v0.x * v0.x + v0.y * v0.y + v0.z * v0.z + v0.w * v0.w
             + v1.x * v1.x + v1.y * v1.y + v1.z * v1.z + v1.w * v1.w
             + v2.x * v2.x + v2.y * v2.y + v2.z * v2.z + v2.w * v2.w;
#pragma unroll
    for (int off = 32; off > 0; off >>= 1) ss += __shfl_xor(ss, off, 64);
    const float sc = 4.0f / fmaxf(sqrtf(ss), 1e-12f);
    int r;
    r = __builtin_amdgcn_cvt_pk_fp8_f32(v0.x * sc, v0.y * sc, 0, false);
    r = __builtin_amdgcn_cvt_pk_fp8_f32(v0.z * sc, v0.w * sc, r, true);
    orow[lane] = (uint_t)r;
    r = __builtin_amdgcn_cvt_pk_fp8_f32(v1.x * sc, v1.y * sc, 0, false);
    r = __builtin_amdgcn_cvt_pk_fp8_f32(v1.z * sc, v1.w * sc, r, true);
    orow[lane + 64] = (uint_t)r;
    r = __builtin_amdgcn_cvt_pk_fp8_f32(v2.x * sc, v2.y * sc, 0, false);
    r = __builtin_amdgcn_cvt_pk_fp8_f32(v2.z * sc, v2.w * sc, r, true);
    orow[lane + 128] = (uint_t)r;
  } else {
    const int b = blockIdx.x - normBlocks;
    const int nkb = P / 32;                   // blocks along K
    const int bk = b % nkb, bc = b / nkb;
    const int k0 = bk * 32, c0 = bc * 32;
    const int tx = threadIdx.x & 31, ty = threadIdx.x >> 5;   // ty 0..7
#pragma unroll
    for (int r = 0; r < 4; ++r) {
      const int c = c0 + tx;
      tile[ty + r * 8][tx] = (c < C) ? pc[(size_t)(k0 + ty + r * 8) * C + c] : 0.f;
    }
    __syncthreads();
#pragma unroll
    for (int r = 0; r < 4; ++r)
      pcT[(size_t)(c0 + ty + r * 8) * P + k0 + tx] =
          f32_to_bf16_bits(tile[tx][ty + r * 8]);
  }
}

// ---------------- GEMM1: 128x128-tile fp8 MFMA, B^T layout, XCD-swizzled ----------------
// act[N,P](bf16) = epilogue( h8[N,K] @ p8[P,K]^T ), inputs fp8 e4m3 at scale x4
// (acc = 16 * true dot). BK=64 (64 B/row): 12 K-iters at K=768, 16 KB LDS.
// epilogue: d2 = max(2 - acc/8, 0); act = exp(-tau*sqrt(d2))
__launch_bounds__(256)
__global__ void gemm1_fp8(const uchar_t* __restrict__ A, const uchar_t* __restrict__ B,
                          ushort_t* __restrict__ act, const float* __restrict__ tptr,
                          int K, int ldc, int gx, int gxlog2) {
  __shared__ __align__(16) uchar_t As[128 * 64];
  __shared__ __align__(16) uchar_t Bs[128 * 64];
  const int tid = threadIdx.x;
  const int lane = tid & 63;
  const int wave = tid >> 6;
  const int wm = wave >> 1, wn = wave & 1;      // 2x2 wave grid, 64x64 each

  // de-swizzle linear block id -> (s, t): col-tiles of a row-stripe share an XCD
  const int lid = blockIdx.x;
  const int xcd = lid & 7;
  const int q = lid >> 3;
  const int t = q & (gx - 1);
  const int s = ((q >> gxlog2) << 3) | xcd;
  const int rowBase = s * 128;
  const int colBase = t * 128;

  f32x4 acc[4][4];
#pragma unroll
  for (int i = 0; i < 4; ++i)
#pragma unroll
    for (int j = 0; j < 4; ++j) acc[i][j] = (f32x4){0.f, 0.f, 0.f, 0.f};

  // staging: 64 lanes x 16 B = 1 KB = 16 rows of 64 B; each wave stages 32 rows (2 calls)
  const int lrow = lane >> 2;         // 0..15
  const int lcol = (lane & 3) * 16;   // byte offset in row
  const size_t aOff = (size_t)(rowBase + wave * 32 + lrow) * K + lcol;
  const size_t bOff = (size_t)(colBase + wave * 32 + lrow) * K + lcol;
  const size_t stride16 = (size_t)16 * K;
  uchar_t* ldsA0 = &As[(wave * 32) * 64];
  uchar_t* ldsA1 = &As[(wave * 32 + 16) * 64];
  uchar_t* ldsB0 = &Bs[(wave * 32) * 64];
  uchar_t* ldsB1 = &Bs[(wave * 32 + 16) * 64];

  const int fr = lane & 15;           // fragment row (A) / col (B)
  const int fb = (lane >> 4) * 8;     // byte offset within 32-B k-step

  const int nK = K >> 6;              // BK = 64
  for (int kt = 0; kt < nK; ++kt) {
    const int kb = kt << 6;
    __syncthreads();  // previous tile's LDS reads done
    gld_lds16(A + aOff + kb, ldsA0);
    gld_lds16(A + aOff + stride16 + kb, ldsA1);
    gld_lds16(B + bOff + kb, ldsB0);
    gld_lds16(B + bOff + stride16 + kb, ldsB1);
    __syncthreads();  // staging complete

    long af[4][2], bf[4][2];
#pragma unroll
    for (int i = 0; i < 4; ++i)
#pragma unroll
      for (int ks = 0; ks < 2; ++ks)
        af[i][ks] = *(const long*)&As[(wm * 64 + i * 16 + fr) * 64 + ks * 32 + fb];
#pragma unroll
    for (int j = 0; j < 4; ++j)
#pragma unroll
      for (int ks = 0; ks < 2; ++ks)
        bf[j][ks] = *(const long*)&Bs[(wn * 64 + j * 16 + fr) * 64 + ks * 32 + fb];
#pragma unroll
    for (int i = 0; i < 4; ++i)
#pragma unroll
      for (int j = 0; j < 4; ++j) {
        acc[i][j] = __builtin_amdgcn_mfma_f32_16x16x32_fp8_fp8(af[i][0], bf[j][0], acc[i][j], 0, 0, 0);
        acc[i][j] = __builtin_amdgcn_mfma_f32_16x16x32_fp8_fp8(af[i][1], bf[j][1], acc[i][j], 0, 0, 0);
      }
  }

  float tmp = *tptr;
  const float tau = log1pf(expf(tmp));
  // C/D layout: col = lane&15, row = (lane>>4)*4 + reg   [measured m89/m91]
  const int crow = (lane >> 4) * 4;
  const int ccol = lane & 15;
#pragma unroll
  for (int i = 0; i < 4; ++i) {
#pragma unroll
    for (int j = 0; j < 4; ++j) {
      const int col = colBase + wn * 64 + j * 16 + ccol;
#pragma unroll
      for (int r = 0; r < 4; ++r) {
        const int row = rowBase + wm * 64 + i * 16 + crow + r;
        float d2 = fmaxf(2.0f - acc[i][j][r] * 0.125f, 0.0f);   // acc = 16*dot
        float a = __expf(-tau * sqrtf(d2));
        act[(size_t)row * ldc + col] = f32_to_bf16_bits(a);
      }
    }
  }
}

// ---------------- GEMM2: 128x128-tile bf16 MFMA, B^T layout, XCD-swizzled (R2 core) ----------------
__launch_bounds__(256)
__global__ void gemm2_bf16(const ushort_t* __restrict__ A, const ushort_t* __restrict__ B,
                           float* __restrict__ Cout, int K, int ldc, int ncols,
                           int gx, int gxlog2) {
  __shared__ __align__(16) ushort_t As[128 * 32];
  __shared__ __align__(16) ushort_t Bs[128 * 32];
  const int tid = threadIdx.x;
  const int lane = tid & 63;
  const int wave = tid >> 6;
  const int wm = wave >> 1, wn = wave & 1;

  const int lid = blockIdx.x;
  const int xcd = lid & 7;
  const int q = lid >> 3;
  const int t = q & (gx - 1);
  const int s = ((q >> gxlog2) << 3) | xcd;
  const int rowBase = s * 128;
  const int colBase = t * 128;

  f32x4 acc[4][4];
#pragma unroll
  for (int i = 0; i < 4; ++i)
#pragma unroll
    for (int j = 0; j < 4; ++j) acc[i][j] = (f32x4){0.f, 0.f, 0.f, 0.f};

  const int lrow = lane >> 2;       // 0..15
  const int lcol = (lane & 3) * 8;  // bf16 elems
  const size_t aOff = (size_t)(rowBase + wave * 16 + lrow) * K + lcol;
  const size_t bOff = (size_t)(colBase + wave * 16 + lrow) * K + lcol;
  const size_t stride64 = (size_t)64 * K;
  ushort_t* ldsA0 = &As[(wave * 16) * 32];
  ushort_t* ldsA1 = &As[(64 + wave * 16) * 32];
  ushort_t* ldsB0 = &Bs[(wave * 16) * 32];
  ushort_t* ldsB1 = &Bs[(64 + wave * 16) * 32];

  const int fr = lane & 15;
  const int fk = (lane >> 4) * 8;

  const int nK = K >> 5;
  for (int kt = 0; kt < nK; ++kt) {
    const int kb = kt << 5;
    __syncthreads();
    gld_lds16(A + aOff + kb, ldsA0);
    gld_lds16(A + aOff + stride64 + kb, ldsA1);
    gld_lds16(B + bOff + kb, ldsB0);
    gld_lds16(B + bOff + stride64 + kb, ldsB1);
    __syncthreads();

    bf16x8 af[4], bfr[4];
#pragma unroll
    for (int i = 0; i < 4; ++i)
      af[i] = *(const bf16x8*)&As[(wm * 64 + i * 16 + fr) * 32 + fk];
#pragma unroll
    for (int j = 0; j < 4; ++j)
      bfr[j] = *(const bf16x8*)&Bs[(wn * 64 + j * 16 + fr) * 32 + fk];
#pragma unroll
    for (int i = 0; i < 4; ++i)
#pragma unroll
      for (int j = 0; j < 4; ++j)
        acc[i][j] = __builtin_amdgcn_mfma_f32_16x16x32_bf16(af[i], bfr[j], acc[i][j], 0, 0, 0);
  }

  const int crow = (lane >> 4) * 4;
  const int ccol = lane & 15;
#pragma unroll
  for (int i = 0; i < 4; ++i) {
#pragma unroll
    for (int j = 0; j < 4; ++j) {
      const int col = colBase + wn * 64 + j * 16 + ccol;
#pragma unroll
      for (int r = 0; r < 4; ++r) {
        const int row = rowBase + wm * 64 + i * 16 + crow + r;
        if (col < ncols)
          Cout[(size_t)row * ldc + col] = acc[i][j][r];
      }
    }
  }
}

extern "C" void kernel_launch(void* const* d_in, const int* in_sizes, int n_in,
                              void* d_out, int out_size, void* d_ws, size_t ws_size,
                              hipStream_t stream) {
  const float* h    = (const float*)d_in[0];
  const float* prot = (const float*)d_in[1];
  const float* pc   = (const float*)d_in[2];
  const float* temp = (const float*)d_in[3];
  float* out = (float*)d_out;

  const int D = 768;
  const int N = in_sizes[0] / D;          // 16384
  const int P = in_sizes[1] / D;          // 2048
  const int C = in_sizes[2] / P;          // 1000
  const int CP = (C + 127) & ~127;        // 1024 (padded)

  // workspace layout (16B aligned)
  char* ws = (char*)d_ws;
  size_t off = 0;
  uchar_t* h8   = (uchar_t*)(ws + off); off += (size_t)N * D;         // 12.6 MB fp8
  uchar_t* p8   = (uchar_t*)(ws + off); off += (size_t)P * D;         //  1.6 MB fp8
  ushort_t* pcT = (ushort_t*)(ws + off); off += (size_t)CP * P * 2;   //  4.2 MB bf16
  ushort_t* act = (ushort_t*)(ws + off); off += (size_t)N * P * 2;    // 67.1 MB bf16
  (void)ws_size;  // total ~85.5 MB

  // single prep dispatch: normalize (fp8 x4) + transpose (bf16)
  const int normBlocks = (N + P) / 4;                 // 4608
  const int transBlocks = (P / 32) * (CP / 32);       // 2048
  prep<<<normBlocks + transBlocks, 256, 0, stream>>>(
      (const float4*)h, (uint_t*)h8, N, (const float4*)prot, (uint_t*)p8, P,
      pc, pcT, P, C, normBlocks);

  // GEMM1: act[N,P](bf16) = epilogue(h8 @ p8^T), fp8 K=768
  {
    const int GX = P / 128, GY = N / 128;   // 16, 128
    gemm1_fp8<<<GX * GY, 256, 0, stream>>>(h8, p8, act, temp, D, P, GX, 4);
  }
  // GEMM2: out[N,C](f32) = act @ pcT^T, bf16 K=2048
  {
    const int GX = CP / 128, GY = N / 128;  // 8, 128
    gemm2_bf16<<<GX * GY, 256, 0, stream>>>(act, pcT, out, P, C, C, GX, 3);
  }
}

// Round 5
// 263.527 us; speedup vs baseline: 1.1450x; 1.1450x over previous
//
#include <hip/hip_runtime.h>
#include <hip/hip_bf16.h>
#include <math.h>

typedef unsigned short ushort_t;
typedef unsigned char uchar_t;
typedef unsigned int uint_t;
typedef __attribute__((ext_vector_type(8))) short bf16x8;   // 8 bf16 = 4 VGPRs
typedef __attribute__((ext_vector_type(4))) float f32x4;

#define AS1 __attribute__((address_space(1)))
#define AS3 __attribute__((address_space(3)))

__device__ __forceinline__ void gld_lds16(const void* g, void* l) {
  // async global->LDS, 16B per lane; LDS dest = wave-uniform base + lane*16
  __builtin_amdgcn_global_load_lds((const AS1 void*)g, (AS3 void*)l, 16, 0, 0);
}

__device__ __forceinline__ ushort_t f32_to_bf16_bits(float v) {
  __hip_bfloat16 b = __float2bfloat16(v);
  return *(ushort_t*)&b;
}

__device__ __forceinline__ uint_t pack_fp8x4(float4 v, float sc) {
  int r = __builtin_amdgcn_cvt_pk_fp8_f32(v.x * sc, v.y * sc, 0, false);
  r = __builtin_amdgcn_cvt_pk_fp8_f32(v.z * sc, v.w * sc, r, true);
  return (uint_t)r;
}

// ================= tiled operand layout =================
// Unit tile = 16 rows x 64 B, stored contiguously (1024 B). Tile index =
// rowblock * nKtiles + kt. Within a tile row rl, the 64 B is split into chunks
// that are XOR-permuted by a per-row key so MFMA fragment ds_reads are
// bank-conflict-free:
//   fp8  (8-B chunks):  phys_chunk = logical ^ ((rl>>1)&7)   -> 16 distinct
//        bank-pairs per 16-lane phase (zero conflict)
//   bf16 (16-B chunks): phys_chunk = logical ^ ((rl>>1)&3)   -> 2-way floor (free)
// Staging global_load_lds copies a tile verbatim (lane*16), so the LDS image
// equals the global image.

// ---------------- single prep kernel ----------------
// blocks [0, normBlocks): wave-per-row L2-normalize of h then prototypes ->
//   fp8 e4m3 at scale x4 in tiled layout (nK = 12 tiles/row-block).
// blocks [normBlocks, ...): 32x32 transpose of prototype_class [P,C] f32 ->
//   pcT [CP rows, P k] bf16 tiled (nK = P/32), zero-padding rows >= C.
__global__ __launch_bounds__(256) void prep(const float4* __restrict__ h,
                                            uchar_t* __restrict__ h8, int rowsH,
                                            const float4* __restrict__ p,
                                            uchar_t* __restrict__ p8, int rowsP,
                                            const float* __restrict__ pc,
                                            ushort_t* __restrict__ pcT,
                                            int P, int C, int normBlocks) {
  __shared__ float tile[32][33];
  if ((int)blockIdx.x < normBlocks) {
    int r = (blockIdx.x * 256 + threadIdx.x) >> 6;
    const int lane = threadIdx.x & 63;
    const float4* xr;
    uchar_t* o8;
    if (r < rowsH) {
      xr = h + (size_t)r * 192;          // 768 floats = 192 float4
      o8 = h8;
    } else {
      r -= rowsH;
      if (r >= rowsP) return;
      xr = p + (size_t)r * 192;
      o8 = p8;
    }
    float4 v0 = xr[lane];
    float4 v1 = xr[lane + 64];
    float4 v2 = xr[lane + 128];
    float ss = v0.x * v0.x + v0.y * v0.y + v0.z * v0.z + v0.w * v0.w
             + v1.x * v1.x + v1.y * v1.y + v1.z * v1.z + v1.w * v1.w
             + v2.x * v2.x + v2.y * v2.y + v2.z * v2.z + v2.w * v2.w;
#pragma unroll
    for (int off = 32; off > 0; off >>= 1) ss += __shfl_xor(ss, off, 64);
    const float sc = 4.0f / fmaxf(sqrtf(ss), 1e-12f);
    // lane L holds elements 4L..4L+3 of each 256-element group
    const int rb = r >> 4, rl = r & 15;
    const int key = (rl >> 1) & 7;
    const int cc = (lane & 15) >> 1;                  // logical 8-B chunk
    const int cphys = ((cc ^ key) << 3) + ((lane & 1) << 2);
    const int ktb = lane >> 4;                        // tile within group
    uchar_t* rowbase = o8 + (size_t)rb * 12 * 1024 + rl * 64 + cphys;
    *(uint_t*)(rowbase + (size_t)(ktb) * 1024)     = pack_fp8x4(v0, sc);
    *(uint_t*)(rowbase + (size_t)(4 + ktb) * 1024) = pack_fp8x4(v1, sc);
    *(uint_t*)(rowbase + (size_t)(8 + ktb) * 1024) = pack_fp8x4(v2, sc);
  } else {
    const int b = blockIdx.x - normBlocks;
    const int nkb = P / 32;                   // k-tiles per pcT row-block (=64)
    const int bk = b % nkb, bc = b / nkb;
    const int k0 = bk * 32, c0 = bc * 32;
    const int tx = threadIdx.x & 31, ty = threadIdx.x >> 5;   // ty 0..7
#pragma unroll
    for (int rr = 0; rr < 4; ++rr) {
      const int c = c0 + tx;
      tile[ty + rr * 8][tx] = (c < C) ? pc[(size_t)(k0 + ty + rr * 8) * C + c] : 0.f;
    }
    __syncthreads();
    const int c2 = tx >> 3, off = tx & 7;
#pragma unroll
    for (int rr = 0; rr < 4; ++rr) {
      const int row = c0 + ty + rr * 8;       // pcT row (class dim)
      const int rb = row >> 4, rl = row & 15;
      const int key4 = (rl >> 1) & 3;
      size_t us = (((size_t)rb * nkb + bk) * 16 + rl) * 32 + ((c2 ^ key4) << 3) + off;
      pcT[us] = f32_to_bf16_bits(tile[tx][ty + rr * 8]);
    }
  }
}

// ---------------- GEMM1: 128x128-tile fp8 MFMA, tiled operands, XCD-swizzled ----------------
// act[N,P](bf16 tiled) = epilogue( h8 @ p8^T ), inputs fp8 e4m3 at scale x4
// (acc = 16*dot). BK=64, nK=12 iters. epilogue: exp(-tau*sqrt(max(2-acc/8,0))).
__launch_bounds__(256)
__global__ void gemm1_fp8(const uchar_t* __restrict__ A, const uchar_t* __restrict__ B,
                          ushort_t* __restrict__ act, const float* __restrict__ tptr,
                          int nK, int actKT, int gx, int gxlog2) {
  __shared__ __align__(16) uchar_t As[8192];
  __shared__ __align__(16) uchar_t Bs[8192];
  const int tid = threadIdx.x, lane = tid & 63, wave = tid >> 6;
  const int wm = wave >> 1, wn = wave & 1;      // 2x2 wave grid, 64x64 each
  const int lid = blockIdx.x, xcd = lid & 7, q = lid >> 3;
  const int t = q & (gx - 1);
  const int s = ((q >> gxlog2) << 3) | xcd;

  f32x4 acc[4][4];
#pragma unroll
  for (int i = 0; i < 4; ++i)
#pragma unroll
    for (int j = 0; j < 4; ++j) acc[i][j] = (f32x4){0.f, 0.f, 0.f, 0.f};

  // staging: each wave copies tiles (2w, 2w+1) of A and B; 1 KB contiguous per call
  const uchar_t* aG0 = A + (size_t)(s * 8 + wave * 2) * nK * 1024 + lane * 16;
  const uchar_t* aG1 = aG0 + (size_t)nK * 1024;
  const uchar_t* bG0 = B + (size_t)(t * 8 + wave * 2) * nK * 1024 + lane * 16;
  const uchar_t* bG1 = bG0 + (size_t)nK * 1024;
  uchar_t* lA0 = &As[(wave * 2) * 1024];
  uchar_t* lA1 = lA0 + 1024;
  uchar_t* lB0 = &Bs[(wave * 2) * 1024];
  uchar_t* lB1 = lB0 + 1024;

  const int fr = lane & 15, g = lane >> 4;
  const int key = (fr >> 1) & 7;
  const int c0 = ((g ^ key) << 3);              // ks=0: logical chunk g
  const int c1 = (((g | 4) ^ key) << 3);        // ks=1: logical chunk g+4
  const int rA = fr * 64;

  for (int kt = 0; kt < nK; ++kt) {
    const size_t off = (size_t)kt * 1024;
    __syncthreads();  // previous tile's LDS reads done
    gld_lds16(aG0 + off, lA0);
    gld_lds16(aG1 + off, lA1);
    gld_lds16(bG0 + off, lB0);
    gld_lds16(bG1 + off, lB1);
    __syncthreads();  // staging complete

    long a0[4], a1[4], b0[4], b1[4];
#pragma unroll
    for (int i = 0; i < 4; ++i) {
      const int base = (wm * 4 + i) * 1024 + rA;
      a0[i] = *(const long*)&As[base + c0];
      a1[i] = *(const long*)&As[base + c1];
    }
#pragma unroll
    for (int j = 0; j < 4; ++j) {
      const int base = (wn * 4 + j) * 1024 + rA;
      b0[j] = *(const long*)&Bs[base + c0];
      b1[j] = *(const long*)&Bs[base + c1];
    }
#pragma unroll
    for (int i = 0; i < 4; ++i)
#pragma unroll
      for (int j = 0; j < 4; ++j) {
        acc[i][j] = __builtin_amdgcn_mfma_f32_16x16x32_fp8_fp8(a0[i], b0[j], acc[i][j], 0, 0, 0);
        acc[i][j] = __builtin_amdgcn_mfma_f32_16x16x32_fp8_fp8(a1[i], b1[j], acc[i][j], 0, 0, 0);
      }
  }

  float tmp = *tptr;
  const float tau = log1pf(expf(tmp));
  // C/D layout: col = lane&15, row = (lane>>4)*4 + reg   [measured m89/m91]
  const int crow = g * 4, ccol = fr;
  const int rowB = s * 128 + wm * 64, colB = t * 128 + wn * 64;
#pragma unroll
  for (int i = 0; i < 4; ++i)
#pragma unroll
    for (int j = 0; j < 4; ++j) {
      const int col = colB + j * 16 + ccol;
      const size_t ktile = col >> 5;
      const int c2 = (col >> 3) & 3, co = col & 7;
#pragma unroll
      for (int rr = 0; rr < 4; ++rr) {
        const int row = rowB + i * 16 + crow + rr;
        const int rb = row >> 4, rl = row & 15;
        const int key4 = (rl >> 1) & 3;
        float d2 = fmaxf(2.0f - acc[i][j][rr] * 0.125f, 0.0f);   // acc = 16*dot
        float a = __expf(-tau * sqrtf(d2));
        act[(((size_t)rb * actKT + ktile) * 16 + rl) * 32 + ((c2 ^ key4) << 3) + co] =
            f32_to_bf16_bits(a);
      }
    }
}

// ---------------- GEMM2: 128x128-tile bf16 MFMA, tiled operands, XCD-swizzled ----------------
// out[N,C](f32 row-major) = act[N,P] @ pcT[CP,P]^T, both operands bf16 tiled. BK=32.
__launch_bounds__(256)
__global__ void gemm2_bf16(const ushort_t* __restrict__ A, const ushort_t* __restrict__ B,
                           float* __restrict__ out, int nK, int ldc, int ncols,
                           int gx, int gxlog2) {
  __shared__ __align__(16) ushort_t As[4096];   // 8 tiles x 512 ushorts = 8 KB
  __shared__ __align__(16) ushort_t Bs[4096];
  const int tid = threadIdx.x, lane = tid & 63, wave = tid >> 6;
  const int wm = wave >> 1, wn = wave & 1;
  const int lid = blockIdx.x, xcd = lid & 7, q = lid >> 3;
  const int t = q & (gx - 1);
  const int s = ((q >> gxlog2) << 3) | xcd;

  f32x4 acc[4][4];
#pragma unroll
  for (int i = 0; i < 4; ++i)
#pragma unroll
    for (int j = 0; j < 4; ++j) acc[i][j] = (f32x4){0.f, 0.f, 0.f, 0.f};

  const ushort_t* aG0 = A + (size_t)(s * 8 + wave * 2) * nK * 512 + lane * 8;
  const ushort_t* aG1 = aG0 + (size_t)nK * 512;
  const ushort_t* bG0 = B + (size_t)(t * 8 + wave * 2) * nK * 512 + lane * 8;
  const ushort_t* bG1 = bG0 + (size_t)nK * 512;
  ushort_t* lA0 = &As[(wave * 2) * 512];
  ushort_t* lA1 = lA0 + 512;
  ushort_t* lB0 = &Bs[(wave * 2) * 512];
  ushort_t* lB1 = lB0 + 512;

  const int fr = lane & 15, g = lane >> 4;
  const int key4 = (fr >> 1) & 3;
  const int cph = (g ^ key4) << 3;    // ushort offset of 16-B physical chunk
  const int rA = fr * 32;

  for (int kt = 0; kt < nK; ++kt) {
    const size_t off = (size_t)kt * 512;
    __syncthreads();
    gld_lds16(aG0 + off, lA0);
    gld_lds16(aG1 + off, lA1);
    gld_lds16(bG0 + off, lB0);
    gld_lds16(bG1 + off, lB1);
    __syncthreads();

    bf16x8 af[4], bfr[4];
#pragma unroll
    for (int i = 0; i < 4; ++i)
      af[i] = *(const bf16x8*)&As[(wm * 4 + i) * 512 + rA + cph];
#pragma unroll
    for (int j = 0; j < 4; ++j)
      bfr[j] = *(const bf16x8*)&Bs[(wn * 4 + j) * 512 + rA + cph];
#pragma unroll
    for (int i = 0; i < 4; ++i)
#pragma unroll
      for (int j = 0; j < 4; ++j)
        acc[i][j] = __builtin_amdgcn_mfma_f32_16x16x32_bf16(af[i], bfr[j], acc[i][j], 0, 0, 0);
  }

  const int crow = g * 4, ccol = fr;
  const int rowB = s * 128 + wm * 64, colB = t * 128 + wn * 64;
#pragma unroll
  for (int i = 0; i < 4; ++i)
#pragma unroll
    for (int j = 0; j < 4; ++j) {
      const int col = colB + j * 16 + ccol;
      if (col < ncols) {
#pragma unroll
        for (int rr = 0; rr < 4; ++rr) {
          const int row = rowB + i * 16 + crow + rr;
          out[(size_t)row * ldc + col] = acc[i][j][rr];
        }
      }
    }
}

extern "C" void kernel_launch(void* const* d_in, const int* in_sizes, int n_in,
                              void* d_out, int out_size, void* d_ws, size_t ws_size,
                              hipStream_t stream) {
  const float* h    = (const float*)d_in[0];
  const float* prot = (const float*)d_in[1];
  const float* pc   = (const float*)d_in[2];
  const float* temp = (const float*)d_in[3];
  float* out = (float*)d_out;

  const int D = 768;
  const int N = in_sizes[0] / D;          // 16384
  const int P = in_sizes[1] / D;          // 2048
  const int C = in_sizes[2] / P;          // 1000
  const int CP = (C + 127) & ~127;        // 1024 (padded)

  // workspace layout (16B aligned), all tiled
  char* ws = (char*)d_ws;
  size_t off = 0;
  uchar_t* h8   = (uchar_t*)(ws + off); off += (size_t)N * D;         // 12.6 MB fp8
  uchar_t* p8   = (uchar_t*)(ws + off); off += (size_t)P * D;         //  1.6 MB fp8
  ushort_t* pcT = (ushort_t*)(ws + off); off += (size_t)CP * P * 2;   //  4.2 MB bf16
  ushort_t* act = (ushort_t*)(ws + off); off += (size_t)N * P * 2;    // 67.1 MB bf16
  (void)ws_size;  // total ~85.5 MB

  // single prep dispatch: normalize (fp8 x4, tiled) + transpose (bf16, tiled)
  const int normBlocks = (N + P) / 4;                 // 4608
  const int transBlocks = (P / 32) * (CP / 32);       // 2048
  prep<<<normBlocks + transBlocks, 256, 0, stream>>>(
      (const float4*)h, h8, N, (const float4*)prot, p8, P,
      pc, pcT, P, C, normBlocks);

  // GEMM1: act[N,P](bf16 tiled) = epilogue(h8 @ p8^T), fp8 nK=12
  {
    const int GX = P / 128, GY = N / 128;   // 16, 128
    gemm1_fp8<<<GX * GY, 256, 0, stream>>>(h8, p8, act, temp, D / 64, P / 32, GX, 4);
  }
  // GEMM2: out[N,C](f32) = act @ pcT^T, bf16 nK=64
  {
    const int GX = CP / 128, GY = N / 128;  // 8, 128
    gemm2_bf16<<<GX * GY, 256, 0, stream>>>(act, pcT, out, P / 32, C, C, GX, 3);
  }
}

// Round 6
// 241.654 us; speedup vs baseline: 1.2487x; 1.0905x over previous
//
#include <hip/hip_runtime.h>
#include <hip/hip_bf16.h>
#include <math.h>

typedef unsigned short ushort_t;
typedef unsigned char uchar_t;
typedef unsigned int uint_t;
typedef __attribute__((ext_vector_type(8))) short bf16x8;   // 8 bf16 = 4 VGPRs
typedef __attribute__((ext_vector_type(4))) float f32x4;

#define AS1 __attribute__((address_space(1)))
#define AS3 __attribute__((address_space(3)))

__device__ __forceinline__ void gld_lds16(const void* g, void* l) {
  // async global->LDS, 16B per lane; LDS dest = wave-uniform base + lane*16
  __builtin_amdgcn_global_load_lds((const AS1 void*)g, (AS3 void*)l, 16, 0, 0);
}

__device__ __forceinline__ ushort_t f32_to_bf16_bits(float v) {
  __hip_bfloat16 b = __float2bfloat16(v);
  return *(ushort_t*)&b;
}

__device__ __forceinline__ uint_t pack_fp8x4(float4 v, float sc) {
  int r = __builtin_amdgcn_cvt_pk_fp8_f32(v.x * sc, v.y * sc, 0, false);
  r = __builtin_amdgcn_cvt_pk_fp8_f32(v.z * sc, v.w * sc, r, true);
  return (uint_t)r;
}

// ================= tiled operand layout =================
// Unit tile = 16 rows x 64 B, stored contiguously (1024 B). Tile index =
// rowblock * nKtiles + kt. Within a tile row rl, the 64 B is split into chunks
// XOR-permuted by a per-row key so MFMA fragment ds_reads are conflict-free:
//   fp8  (8-B chunks):  phys = logical ^ ((rl>>1)&7)   [R5: conflicts -> 0]
//   bf16 (16-B chunks): phys = logical ^ ((rl>>1)&3)   [2-way floor, free]
// global_load_lds copies tiles verbatim, so the LDS image equals the global image.

// ---------------- single prep kernel ----------------
__global__ __launch_bounds__(256) void prep(const float4* __restrict__ h,
                                            uchar_t* __restrict__ h8, int rowsH,
                                            const float4* __restrict__ p,
                                            uchar_t* __restrict__ p8, int rowsP,
                                            const float* __restrict__ pc,
                                            ushort_t* __restrict__ pcT,
                                            int P, int C, int normBlocks) {
  __shared__ float tile[32][33];
  if ((int)blockIdx.x < normBlocks) {
    int r = (blockIdx.x * 256 + threadIdx.x) >> 6;
    const int lane = threadIdx.x & 63;
    const float4* xr;
    uchar_t* o8;
    if (r < rowsH) {
      xr = h + (size_t)r * 192;          // 768 floats = 192 float4
      o8 = h8;
    } else {
      r -= rowsH;
      if (r >= rowsP) return;
      xr = p + (size_t)r * 192;
      o8 = p8;
    }
    float4 v0 = xr[lane];
    float4 v1 = xr[lane + 64];
    float4 v2 = xr[lane + 128];
    float ss = v0.x * v0.x + v0.y * v0.y + v0.z * v0.z + v0.w * v0.w
             + v1.x * v1.x + v1.y * v1.y + v1.z * v1.z + v1.w * v1.w
             + v2.x * v2.x + v2.y * v2.y + v2.z * v2.z + v2.w * v2.w;
#pragma unroll
    for (int off = 32; off > 0; off >>= 1) ss += __shfl_xor(ss, off, 64);
    const float sc = 4.0f / fmaxf(sqrtf(ss), 1e-12f);
    // lane L holds elements 4L..4L+3 of each 256-element group
    const int rb = r >> 4, rl = r & 15;
    const int key = (rl >> 1) & 7;
    const int cc = (lane & 15) >> 1;                  // logical 8-B chunk
    const int cphys = ((cc ^ key) << 3) + ((lane & 1) << 2);
    const int ktb = lane >> 4;                        // tile within group
    uchar_t* rowbase = o8 + (size_t)rb * 12 * 1024 + rl * 64 + cphys;
    *(uint_t*)(rowbase + (size_t)(ktb) * 1024)     = pack_fp8x4(v0, sc);
    *(uint_t*)(rowbase + (size_t)(4 + ktb) * 1024) = pack_fp8x4(v1, sc);
    *(uint_t*)(rowbase + (size_t)(8 + ktb) * 1024) = pack_fp8x4(v2, sc);
  } else {
    const int b = blockIdx.x - normBlocks;
    const int nkb = P / 32;                   // k-tiles per pcT row-block (=64)
    const int bk = b % nkb, bc = b / nkb;
    const int k0 = bk * 32, c0 = bc * 32;
    const int tx = threadIdx.x & 31, ty = threadIdx.x >> 5;   // ty 0..7
#pragma unroll
    for (int rr = 0; rr < 4; ++rr) {
      const int c = c0 + tx;
      tile[ty + rr * 8][tx] = (c < C) ? pc[(size_t)(k0 + ty + rr * 8) * C + c] : 0.f;
    }
    __syncthreads();
    const int c2 = tx >> 3, off = tx & 7;
#pragma unroll
    for (int rr = 0; rr < 4; ++rr) {
      const int row = c0 + ty + rr * 8;       // pcT row (class dim)
      const int rb = row >> 4, rl = row & 15;
      const int key4 = (rl >> 1) & 3;
      size_t us = (((size_t)rb * nkb + bk) * 16 + rl) * 32 + ((c2 ^ key4) << 3) + off;
      pcT[us] = f32_to_bf16_bits(tile[tx][ty + rr * 8]);
    }
  }
}

// ---------------- GEMM1: 128x128 fp8 MFMA, BK=128 (6 iters), tiled, XCD-swizzled ----------------
// act[N,P](bf16 tiled) = epilogue( h8 @ p8^T ), fp8 e4m3 scale x4 (acc = 16*dot).
__launch_bounds__(256)
__global__ void gemm1_fp8(const uchar_t* __restrict__ A, const uchar_t* __restrict__ B,
                          ushort_t* __restrict__ act, const float* __restrict__ tptr,
                          int nKt, int actKT, int gx, int gxlog2) {
  __shared__ __align__(16) uchar_t As[16384];   // 8 row-tiles x 2 k-tiles x 1 KB
  __shared__ __align__(16) uchar_t Bs[16384];
  const int tid = threadIdx.x, lane = tid & 63, wave = tid >> 6;
  const int wm = wave >> 1, wn = wave & 1;      // 2x2 wave grid, 64x64 each
  const int lid = blockIdx.x, xcd = lid & 7, q = lid >> 3;
  const int t = q & (gx - 1);
  const int s = ((q >> gxlog2) << 3) | xcd;

  f32x4 acc[4][4];
#pragma unroll
  for (int i = 0; i < 4; ++i)
#pragma unroll
    for (int j = 0; j < 4; ++j) acc[i][j] = (f32x4){0.f, 0.f, 0.f, 0.f};

  // staging: wave covers row-tiles {2w,2w+1} x k-tiles {2kt,2kt+1}; 1 KB per call
  const uchar_t* aW = A + ((size_t)(s * 8 + 2 * wave) * nKt) * 1024 + lane * 16;
  const uchar_t* bW = B + ((size_t)(t * 8 + 2 * wave) * nKt) * 1024 + lane * 16;
  const size_t rstride = (size_t)nKt * 1024;
  uchar_t* lA = &As[wave * 4096];
  uchar_t* lB = &Bs[wave * 4096];

  const int fr = lane & 15, g = lane >> 4;
  const int key = (fr >> 1) & 7;
  const int rowoff = fr * 64;
  const int cp0 = ((g ^ key) << 3);             // ksub=0: logical chunk g
  const int cp1 = (((g | 4) ^ key) << 3);       // ksub=1: logical chunk g+4

  const int nIter = nKt >> 1;                   // 6
  for (int kt = 0; kt < nIter; ++kt) {
    const size_t koff = (size_t)(2 * kt) * 1024;
    __syncthreads();  // previous tile's LDS reads done
    gld_lds16(aW + koff, lA);
    gld_lds16(aW + koff + 1024, lA + 1024);
    gld_lds16(aW + rstride + koff, lA + 2048);
    gld_lds16(aW + rstride + koff + 1024, lA + 3072);
    gld_lds16(bW + koff, lB);
    gld_lds16(bW + koff + 1024, lB + 1024);
    gld_lds16(bW + rstride + koff, lB + 2048);
    gld_lds16(bW + rstride + koff + 1024, lB + 3072);
    __syncthreads();  // staging complete

#pragma unroll
    for (int kk = 0; kk < 2; ++kk) {
#pragma unroll
      for (int ksub = 0; ksub < 2; ++ksub) {
        const int cp = ksub ? cp1 : cp0;
        long a[4], b[4];
#pragma unroll
        for (int i = 0; i < 4; ++i)
          a[i] = *(const long*)&As[((wm * 4 + i) * 2 + kk) * 1024 + rowoff + cp];
#pragma unroll
        for (int j = 0; j < 4; ++j)
          b[j] = *(const long*)&Bs[((wn * 4 + j) * 2 + kk) * 1024 + rowoff + cp];
#pragma unroll
        for (int i = 0; i < 4; ++i)
#pragma unroll
          for (int j = 0; j < 4; ++j)
            acc[i][j] = __builtin_amdgcn_mfma_f32_16x16x32_fp8_fp8(a[i], b[j], acc[i][j], 0, 0, 0);
      }
    }
  }

  float tmp = *tptr;
  const float tau = log1pf(expf(tmp));
  // C/D layout: col = lane&15, row = (lane>>4)*4 + reg   [measured m89/m91]
  const int crow = g * 4, ccol = fr;
  const int rowB = s * 128 + wm * 64, colB = t * 128 + wn * 64;
#pragma unroll
  for (int i = 0; i < 4; ++i)
#pragma unroll
    for (int j = 0; j < 4; ++j) {
      const int col = colB + j * 16 + ccol;
      const size_t ktile = col >> 5;
      const int c2 = (col >> 3) & 3, co = col & 7;
#pragma unroll
      for (int rr = 0; rr < 4; ++rr) {
        const int row = rowB + i * 16 + crow + rr;
        const int rb = row >> 4, rl = row & 15;
        const int key4 = (rl >> 1) & 3;
        float d2 = fmaxf(2.0f - acc[i][j][rr] * 0.125f, 0.0f);   // acc = 16*dot
        float a = __expf(-tau * sqrtf(d2));
        act[(((size_t)rb * actKT + ktile) * 16 + rl) * 32 + ((c2 ^ key4) << 3) + co] =
            f32_to_bf16_bits(a);
      }
    }
}

// ---------------- GEMM2: 128x128 bf16 MFMA, BK=64 (32 iters), tiled, XCD-swizzled ----------------
__launch_bounds__(256)
__global__ void gemm2_bf16(const ushort_t* __restrict__ A, const ushort_t* __restrict__ B,
                           float* __restrict__ out, int nKt, int ldc, int ncols,
                           int gx, int gxlog2) {
  __shared__ __align__(16) ushort_t As[8192];   // 8 row-tiles x 2 k-tiles x 512 = 16 KB
  __shared__ __align__(16) ushort_t Bs[8192];
  const int tid = threadIdx.x, lane = tid & 63, wave = tid >> 6;
  const int wm = wave >> 1, wn = wave & 1;
  const int lid = blockIdx.x, xcd = lid & 7, q = lid >> 3;
  const int t = q & (gx - 1);
  const int s = ((q >> gxlog2) << 3) | xcd;

  f32x4 acc[4][4];
#pragma unroll
  for (int i = 0; i < 4; ++i)
#pragma unroll
    for (int j = 0; j < 4; ++j) acc[i][j] = (f32x4){0.f, 0.f, 0.f, 0.f};

  const ushort_t* aW = A + ((size_t)(s * 8 + 2 * wave) * nKt) * 512 + lane * 8;
  const ushort_t* bW = B + ((size_t)(t * 8 + 2 * wave) * nKt) * 512 + lane * 8;
  const size_t rstride = (size_t)nKt * 512;
  ushort_t* lA = &As[wave * 2048];
  ushort_t* lB = &Bs[wave * 2048];

  const int fr = lane & 15, g = lane >> 4;
  const int key4 = (fr >> 1) & 3;
  const int cph = (g ^ key4) << 3;    // ushort offset of 16-B physical chunk
  const int rowoff = fr * 32;

  const int nIter = nKt >> 1;         // 32
  for (int kt = 0; kt < nIter; ++kt) {
    const size_t koff = (size_t)(2 * kt) * 512;
    __syncthreads();
    gld_lds16(aW + koff, lA);
    gld_lds16(aW + koff + 512, lA + 512);
    gld_lds16(aW + rstride + koff, lA + 1024);
    gld_lds16(aW + rstride + koff + 512, lA + 1536);
    gld_lds16(bW + koff, lB);
    gld_lds16(bW + koff + 512, lB + 512);
    gld_lds16(bW + rstride + koff, lB + 1024);
    gld_lds16(bW + rstride + koff + 512, lB + 1536);
    __syncthreads();

#pragma unroll
    for (int kk = 0; kk < 2; ++kk) {
      bf16x8 af[4], bfr[4];
#pragma unroll
      for (int i = 0; i < 4; ++i)
        af[i] = *(const bf16x8*)&As[((wm * 4 + i) * 2 + kk) * 512 + rowoff + cph];
#pragma unroll
      for (int j = 0; j < 4; ++j)
        bfr[j] = *(const bf16x8*)&Bs[((wn * 4 + j) * 2 + kk) * 512 + rowoff + cph];
#pragma unroll
      for (int i = 0; i < 4; ++i)
#pragma unroll
        for (int j = 0; j < 4; ++j)
          acc[i][j] = __builtin_amdgcn_mfma_f32_16x16x32_bf16(af[i], bfr[j], acc[i][j], 0, 0, 0);
    }
  }

  const int crow = g * 4, ccol = fr;
  const int rowB = s * 128 + wm * 64, colB = t * 128 + wn * 64;
#pragma unroll
  for (int i = 0; i < 4; ++i)
#pragma unroll
    for (int j = 0; j < 4; ++j) {
      const int col = colB + j * 16 + ccol;
      if (col < ncols) {
#pragma unroll
        for (int rr = 0; rr < 4; ++rr) {
          const int row = rowB + i * 16 + crow + rr;
          out[(size_t)row * ldc + col] = acc[i][j][rr];
        }
      }
    }
}

extern "C" void kernel_launch(void* const* d_in, const int* in_sizes, int n_in,
                              void* d_out, int out_size, void* d_ws, size_t ws_size,
                              hipStream_t stream) {
  const float* h    = (const float*)d_in[0];
  const float* prot = (const float*)d_in[1];
  const float* pc   = (const float*)d_in[2];
  const float* temp = (const float*)d_in[3];
  float* out = (float*)d_out;

  const int D = 768;
  const int N = in_sizes[0] / D;          // 16384
  const int P = in_sizes[1] / D;          // 2048
  const int C = in_sizes[2] / P;          // 1000
  const int CP = (C + 127) & ~127;        // 1024 (padded)

  // workspace layout (16B aligned), all tiled
  char* ws = (char*)d_ws;
  size_t off = 0;
  uchar_t* h8   = (uchar_t*)(ws + off); off += (size_t)N * D;         // 12.6 MB fp8
  uchar_t* p8   = (uchar_t*)(ws + off); off += (size_t)P * D;         //  1.6 MB fp8
  ushort_t* pcT = (ushort_t*)(ws + off); off += (size_t)CP * P * 2;   //  4.2 MB bf16
  ushort_t* act = (ushort_t*)(ws + off); off += (size_t)N * P * 2;    // 67.1 MB bf16
  (void)ws_size;  // total ~85.5 MB

  // single prep dispatch: normalize (fp8 x4, tiled) + transpose (bf16, tiled)
  const int normBlocks = (N + P) / 4;                 // 4608
  const int transBlocks = (P / 32) * (CP / 32);       // 2048
  prep<<<normBlocks + transBlocks, 256, 0, stream>>>(
      (const float4*)h, h8, N, (const float4*)prot, p8, P,
      pc, pcT, P, C, normBlocks);

  // GEMM1: act[N,P](bf16 tiled) = epilogue(h8 @ p8^T), fp8, BK=128
  {
    const int GX = P / 128, GY = N / 128;   // 16, 128
    gemm1_fp8<<<GX * GY, 256, 0, stream>>>(h8, p8, act, temp, D / 64, P / 32, GX, 4);
  }
  // GEMM2: out[N,C](f32) = act @ pcT^T, bf16, BK=64
  {
    const int GX = CP / 128, GY = N / 128;  // 8, 128
    gemm2_bf16<<<GX * GY, 256, 0, stream>>>(act, pcT, out, P / 32, C, C, GX, 3);
  }
}